// Round 1
// baseline (659.062 us; speedup 1.0000x reference)
//
#include <hip/hip_runtime.h>

#define IN_DIM 128
#define HID 64

// ---------------- degree / norm ----------------

__global__ __launch_bounds__(256) void deg_kernel(const int* __restrict__ rows,
                                                  float* __restrict__ norm, int E) {
    int e = blockIdx.x * blockDim.x + threadIdx.x;
    if (e < E) atomicAdd(&norm[rows[e]], 1.0f);
}

__global__ __launch_bounds__(256) void norm_kernel(float* __restrict__ norm, int N) {
    int i = blockIdx.x * blockDim.x + threadIdx.x;
    if (i < N) norm[i] = rsqrtf(1.0f + norm[i]);
}

// ---------------- fused linear (x@W + b) + input scale ----------------
// 16 rows per block, 256 threads: thread (r4, c) computes 4 rows x 1 col.
// W (128x64 f32 = 32KB) + x tile (16x128 = 8KB) staged in LDS.

__global__ __launch_bounds__(256) void linear_kernel(
        const float* __restrict__ x, const float* __restrict__ W,
        const float* __restrict__ b, const float* __restrict__ norm,
        float* __restrict__ xs, int N) {
    __shared__ float Wl[IN_DIM * HID];
    __shared__ float bl[HID];
    __shared__ float xl[16 * IN_DIM];
    const int tid = threadIdx.x;

    for (int i = tid; i < IN_DIM * HID; i += 256) Wl[i] = W[i];
    if (tid < HID) bl[tid] = b[tid];

    const int row0 = blockIdx.x * 16;
    for (int i = tid; i < 16 * IN_DIM; i += 256) {
        int r = i >> 7, k = i & (IN_DIM - 1);
        int gr = row0 + r;
        xl[i] = (gr < N) ? x[(size_t)gr * IN_DIM + k] : 0.0f;
    }
    __syncthreads();

    const int c = tid & 63;
    const int r4 = tid >> 6;  // 0..3
    for (int rr = 0; rr < 4; ++rr) {
        int r = r4 * 4 + rr;          // 0..15
        int gr = row0 + r;
        if (gr >= N) continue;
        float sum = bl[c];
        #pragma unroll 16
        for (int k = 0; k < IN_DIM; ++k)
            sum = fmaf(xl[r * IN_DIM + k], Wl[k * HID + c], sum);
        // only norm*h is needed downstream (h itself re-derivable); store xs = norm*h
        xs[(size_t)gr * HID + c] = norm[gr] * sum;
    }
}

// ---------------- edge scatter: agg[row] += xs[col] ----------------
// one wave (64 lanes) per edge; lane = feature index -> fully coalesced
// 256B gather + 256B atomic segment per edge.

__global__ __launch_bounds__(256) void scatter_kernel(
        const int* __restrict__ rows, const int* __restrict__ cols,
        const float* __restrict__ xs, float* __restrict__ agg, int E) {
    long long tid = (long long)blockIdx.x * blockDim.x + threadIdx.x;
    int e = (int)(tid >> 6);
    int f = (int)(tid & 63);
    if (e >= E) return;
    int r = rows[e];
    int c = cols[e];
    float v = xs[(size_t)c * HID + f];
    atomicAdd(&agg[(size_t)r * HID + f], v);
}

// ---------------- finalize: h = norm*(agg + xs); xs_next = norm*h ----------------
// float4 over N*HID; writes d_out only on last layer, xs in place otherwise.

__global__ __launch_bounds__(256) void finalize_kernel(
        const float* __restrict__ agg, float* __restrict__ xs,
        const float* __restrict__ norm, float* __restrict__ out,
        int N, int last) {
    int tid = blockIdx.x * blockDim.x + threadIdx.x;  // over N*16 float4 chunks
    if (tid >= N * (HID / 4)) return;
    int node = tid >> 4;
    float nv = norm[node];
    float4 a = reinterpret_cast<const float4*>(agg)[tid];
    float4 s = reinterpret_cast<const float4*>(xs)[tid];
    float4 h;
    h.x = nv * (a.x + s.x);
    h.y = nv * (a.y + s.y);
    h.z = nv * (a.z + s.z);
    h.w = nv * (a.w + s.w);
    if (last) {
        reinterpret_cast<float4*>(out)[tid] = h;
    } else {
        float4 xn;
        xn.x = nv * h.x;
        xn.y = nv * h.y;
        xn.z = nv * h.z;
        xn.w = nv * h.w;
        reinterpret_cast<float4*>(xs)[tid] = xn;
    }
}

extern "C" void kernel_launch(void* const* d_in, const int* in_sizes, int n_in,
                              void* d_out, int out_size, void* d_ws, size_t ws_size,
                              hipStream_t stream) {
    const float* x  = (const float*)d_in[0];
    const int*   ei = (const int*)d_in[1];
    const float* W  = (const float*)d_in[2];
    const float* b  = (const float*)d_in[3];
    float* out = (float*)d_out;

    const int N = in_sizes[0] / IN_DIM;
    const int E = in_sizes[1] / 2;
    const int* rows = ei;        // edge_index[0]
    const int* cols = ei + E;    // edge_index[1]

    // workspace layout (floats): norm[N] | xs[N*HID] | agg[N*HID]
    float* norm = (float*)d_ws;
    size_t nAlign = ((size_t)N + 63) & ~(size_t)63;
    float* xs  = norm + nAlign;
    float* agg = xs + (size_t)N * HID;

    // 1) degree -> norm
    hipMemsetAsync(norm, 0, (size_t)N * sizeof(float), stream);
    deg_kernel<<<(E + 255) / 256, 256, 0, stream>>>(rows, norm, E);
    norm_kernel<<<(N + 255) / 256, 256, 0, stream>>>(norm, N);

    // 2) xs0 = norm * (x @ W + b)
    linear_kernel<<<(N + 15) / 16, 256, 0, stream>>>(x, W, b, norm, xs, N);

    // 3) three GCN conv layers
    const long long scat_threads = (long long)E * 64;
    const int scat_blocks = (int)((scat_threads + 255) / 256);
    const int fin_blocks = (N * (HID / 4) + 255) / 256;
    for (int layer = 0; layer < 3; ++layer) {
        hipMemsetAsync(agg, 0, (size_t)N * HID * sizeof(float), stream);
        scatter_kernel<<<scat_blocks, 256, 0, stream>>>(rows, cols, xs, agg, E);
        finalize_kernel<<<fin_blocks, 256, 0, stream>>>(agg, xs, norm, out, N,
                                                        layer == 2 ? 1 : 0);
    }
}

// Round 2
// 363.373 us; speedup vs baseline: 1.8137x; 1.8137x over previous
//
#include <hip/hip_runtime.h>

#define IN_DIM 128
#define HID 64

// ================= CSR build =================

__global__ __launch_bounds__(256) void hist_kernel(const int* __restrict__ rows,
                                                   int* __restrict__ cnt, int E) {
    int e = blockIdx.x * blockDim.x + threadIdx.x;
    if (e < E) atomicAdd(&cnt[rows[e]], 1);
}

// single-block exclusive scan over cnt -> row_ptr (+cursor copy), norm = rsqrt(1+deg)
__global__ __launch_bounds__(1024) void scan_kernel(const int* __restrict__ cnt,
                                                    int* __restrict__ row_ptr,
                                                    int* __restrict__ cursor,
                                                    float* __restrict__ norm, int N) {
    __shared__ int sdata[1024];
    __shared__ int s_carry;
    const int tid = threadIdx.x;
    if (tid == 0) s_carry = 0;
    __syncthreads();
    for (int base = 0; base < N; base += 1024) {
        int i = base + tid;
        int v = (i < N) ? cnt[i] : 0;
        sdata[tid] = v;
        __syncthreads();
        #pragma unroll
        for (int off = 1; off < 1024; off <<= 1) {
            int t = (tid >= off) ? sdata[tid - off] : 0;
            __syncthreads();
            sdata[tid] += t;
            __syncthreads();
        }
        int incl = sdata[tid];
        int excl = incl - v;
        int carry = s_carry;
        if (i < N) {
            int p = carry + excl;
            row_ptr[i] = p;
            cursor[i]  = p;
            norm[i]    = rsqrtf(1.0f + (float)v);
        }
        __syncthreads();
        if (tid == 1023) s_carry = carry + incl;
        __syncthreads();
    }
    if (tid == 0) row_ptr[N] = s_carry;
}

__global__ __launch_bounds__(256) void fill_kernel(const int* __restrict__ rows,
                                                   const int* __restrict__ cols,
                                                   int* __restrict__ cursor,
                                                   int* __restrict__ col_sorted, int E) {
    int e = blockIdx.x * blockDim.x + threadIdx.x;
    if (e >= E) return;
    int r = rows[e];
    int pos = atomicAdd(&cursor[r], 1);
    col_sorted[pos] = cols[e];
}

// ================= fused linear (x@W + b) * norm =================
// 16 rows/block, 256 threads; W (32 KB) + x tile (8 KB) in LDS.

__global__ __launch_bounds__(256) void linear_kernel(
        const float* __restrict__ x, const float* __restrict__ W,
        const float* __restrict__ b, const float* __restrict__ norm,
        float* __restrict__ xs, int N) {
    __shared__ float Wl[IN_DIM * HID];
    __shared__ float bl[HID];
    __shared__ float xl[16 * IN_DIM];
    const int tid = threadIdx.x;

    for (int i = tid; i < IN_DIM * HID; i += 256) Wl[i] = W[i];
    if (tid < HID) bl[tid] = b[tid];

    const int row0 = blockIdx.x * 16;
    for (int i = tid; i < 16 * IN_DIM; i += 256) {
        int r = i >> 7, k = i & (IN_DIM - 1);
        int gr = row0 + r;
        xl[i] = (gr < N) ? x[(size_t)gr * IN_DIM + k] : 0.0f;
    }
    __syncthreads();

    const int c = tid & 63;
    const int r4 = tid >> 6;
    for (int rr = 0; rr < 4; ++rr) {
        int r = r4 * 4 + rr;
        int gr = row0 + r;
        if (gr >= N) continue;
        float sum = bl[c];
        #pragma unroll 16
        for (int k = 0; k < IN_DIM; ++k)
            sum = fmaf(xl[r * IN_DIM + k], Wl[k * HID + c], sum);
        xs[(size_t)gr * HID + c] = norm[gr] * sum;
    }
}

// ================= fused GCN layer =================
// one wave per node, lane = feature; gather-sum neighbors from CSR,
// write norm*(acc+self) (last layer -> h) or norm^2*(acc+self) (-> xs_next).

__global__ __launch_bounds__(256) void layer_kernel(
        const int* __restrict__ row_ptr, const int* __restrict__ col_sorted,
        const float* __restrict__ xin, const float* __restrict__ norm,
        float* __restrict__ xout, int N, int last) {
    int node = (blockIdx.x * blockDim.x + threadIdx.x) >> 6;
    int lane = threadIdx.x & 63;
    if (node >= N) return;

    int s = row_ptr[node];
    int e = row_ptr[node + 1];
    float acc = 0.0f;
    int j = s;
    for (; j + 4 <= e; j += 4) {
        int c0 = col_sorted[j];
        int c1 = col_sorted[j + 1];
        int c2 = col_sorted[j + 2];
        int c3 = col_sorted[j + 3];
        float v0 = xin[(size_t)c0 * HID + lane];
        float v1 = xin[(size_t)c1 * HID + lane];
        float v2 = xin[(size_t)c2 * HID + lane];
        float v3 = xin[(size_t)c3 * HID + lane];
        acc += (v0 + v1) + (v2 + v3);
    }
    for (; j < e; ++j)
        acc += xin[(size_t)col_sorted[j] * HID + lane];

    float self = xin[(size_t)node * HID + lane];
    float nv = norm[node];
    float h = nv * (acc + self);
    xout[(size_t)node * HID + lane] = last ? h : nv * h;
}

extern "C" void kernel_launch(void* const* d_in, const int* in_sizes, int n_in,
                              void* d_out, int out_size, void* d_ws, size_t ws_size,
                              hipStream_t stream) {
    const float* x  = (const float*)d_in[0];
    const int*   ei = (const int*)d_in[1];
    const float* W  = (const float*)d_in[2];
    const float* b  = (const float*)d_in[3];
    float* out = (float*)d_out;

    const int N = in_sizes[0] / IN_DIM;
    const int E = in_sizes[1] / 2;
    const int* rows = ei;
    const int* cols = ei + E;

    // ws layout (4B units): norm[N] | row_ptr[N+1] | cnt[N] | cursor[N] | col_sorted[E] | xs0[N*HID]
    float* norm      = (float*)d_ws;
    int*   row_ptr   = (int*)(norm + N);
    int*   cnt       = row_ptr + (N + 1);
    int*   cursor    = cnt + N;
    int*   col_sorted= cursor + N;
    float* xs0       = (float*)(col_sorted + E);

    // ---- CSR build (amortized over 3 layers) ----
    hipMemsetAsync(cnt, 0, (size_t)N * sizeof(int), stream);
    hist_kernel<<<(E + 255) / 256, 256, 0, stream>>>(rows, cnt, E);
    scan_kernel<<<1, 1024, 0, stream>>>(cnt, row_ptr, cursor, norm, N);
    fill_kernel<<<(E + 255) / 256, 256, 0, stream>>>(rows, cols, cursor, col_sorted, E);

    // ---- xs0 = norm * (x @ W + b) ----
    linear_kernel<<<(N + 15) / 16, 256, 0, stream>>>(x, W, b, norm, xs0, N);

    // ---- 3 layers, ping-pong xs0 <-> d_out ----
    const int blocks = (N * 64 + 255) / 256;
    layer_kernel<<<blocks, 256, 0, stream>>>(row_ptr, col_sorted, xs0, norm, out, N, 0);
    layer_kernel<<<blocks, 256, 0, stream>>>(row_ptr, col_sorted, out, norm, xs0, N, 0);
    layer_kernel<<<blocks, 256, 0, stream>>>(row_ptr, col_sorted, xs0, norm, out, N, 1);
}

// Round 3
// 278.201 us; speedup vs baseline: 2.3690x; 1.3062x over previous
//
#include <hip/hip_runtime.h>

#define IN_DIM 128
#define HID 64
#define CHUNK 1024   // elements of cnt per scan block

// ================= CSR build =================

__global__ __launch_bounds__(256) void hist_kernel(const int* __restrict__ rows,
                                                   int* __restrict__ cnt, int E) {
    int e = blockIdx.x * blockDim.x + threadIdx.x;
    if (e < E) atomicAdd(&cnt[rows[e]], 1);
}

// phase A: per-chunk sums
__global__ __launch_bounds__(256) void reduce_kernel(const int* __restrict__ cnt,
                                                     int* __restrict__ chunk_sum, int N) {
    __shared__ int sdata[4];  // one per wave
    int base = blockIdx.x * CHUNK + threadIdx.x * 4;
    int s = 0;
    #pragma unroll
    for (int k = 0; k < 4; ++k) {
        int i = base + k;
        if (i < N) s += cnt[i];
    }
    // wave reduce
    #pragma unroll
    for (int off = 32; off >= 1; off >>= 1) s += __shfl_down(s, off, 64);
    int wave = threadIdx.x >> 6;
    if ((threadIdx.x & 63) == 0) sdata[wave] = s;
    __syncthreads();
    if (threadIdx.x == 0)
        chunk_sum[blockIdx.x] = sdata[0] + sdata[1] + sdata[2] + sdata[3];
}

// phase B: scan chunk sums (single small block; nc <= 256)
__global__ __launch_bounds__(256) void chunkscan_kernel(const int* __restrict__ chunk_sum,
                                                        int* __restrict__ chunk_off,
                                                        int* __restrict__ row_ptr_last,
                                                        int nc) {
    __shared__ int s[256];
    int tid = threadIdx.x;
    int v = (tid < nc) ? chunk_sum[tid] : 0;
    s[tid] = v;
    __syncthreads();
    #pragma unroll
    for (int off = 1; off < 256; off <<= 1) {
        int t = (tid >= off) ? s[tid - off] : 0;
        __syncthreads();
        s[tid] += t;
        __syncthreads();
    }
    if (tid < nc) chunk_off[tid] = s[tid] - v;      // exclusive
    if (tid == 255) *row_ptr_last = s[255];          // total edges
}

// phase C: per-chunk exclusive scan + fused norm/cursor emit
__global__ __launch_bounds__(256) void scanout_kernel(const int* __restrict__ cnt,
                                                      const int* __restrict__ chunk_off,
                                                      int* __restrict__ row_ptr,
                                                      int* __restrict__ cursor,
                                                      float* __restrict__ norm, int N) {
    __shared__ int s[256];
    int tid = threadIdx.x;
    int base = blockIdx.x * CHUNK + tid * 4;
    int v[4];
    int tsum = 0;
    #pragma unroll
    for (int k = 0; k < 4; ++k) {
        int i = base + k;
        v[k] = (i < N) ? cnt[i] : 0;
        tsum += v[k];
    }
    s[tid] = tsum;
    __syncthreads();
    #pragma unroll
    for (int off = 1; off < 256; off <<= 1) {
        int t = (tid >= off) ? s[tid - off] : 0;
        __syncthreads();
        s[tid] += t;
        __syncthreads();
    }
    int pos = chunk_off[blockIdx.x] + s[tid] - tsum;  // exclusive start for this thread
    #pragma unroll
    for (int k = 0; k < 4; ++k) {
        int i = base + k;
        if (i < N) {
            row_ptr[i] = pos;
            cursor[i]  = pos;
            norm[i]    = rsqrtf(1.0f + (float)v[k]);
            pos += v[k];
        }
    }
}

__global__ __launch_bounds__(256) void fill_kernel(const int* __restrict__ rows,
                                                   const int* __restrict__ cols,
                                                   int* __restrict__ cursor,
                                                   int* __restrict__ col_sorted, int E) {
    int e = blockIdx.x * blockDim.x + threadIdx.x;
    if (e >= E) return;
    int r = rows[e];
    int pos = atomicAdd(&cursor[r], 1);
    col_sorted[pos] = cols[e];
}

// ================= fused linear (x@W + b) * norm =================

__global__ __launch_bounds__(256) void linear_kernel(
        const float* __restrict__ x, const float* __restrict__ W,
        const float* __restrict__ b, const float* __restrict__ norm,
        float* __restrict__ xs, int N) {
    __shared__ float Wl[IN_DIM * HID];
    __shared__ float bl[HID];
    __shared__ float xl[16 * IN_DIM];
    const int tid = threadIdx.x;

    for (int i = tid; i < IN_DIM * HID; i += 256) Wl[i] = W[i];
    if (tid < HID) bl[tid] = b[tid];

    const int row0 = blockIdx.x * 16;
    for (int i = tid; i < 16 * IN_DIM; i += 256) {
        int r = i >> 7, k = i & (IN_DIM - 1);
        int gr = row0 + r;
        xl[i] = (gr < N) ? x[(size_t)gr * IN_DIM + k] : 0.0f;
    }
    __syncthreads();

    const int c = tid & 63;
    const int r4 = tid >> 6;
    for (int rr = 0; rr < 4; ++rr) {
        int r = r4 * 4 + rr;
        int gr = row0 + r;
        if (gr >= N) continue;
        float sum = bl[c];
        #pragma unroll 16
        for (int k = 0; k < IN_DIM; ++k)
            sum = fmaf(xl[r * IN_DIM + k], Wl[k * HID + c], sum);
        xs[(size_t)gr * HID + c] = norm[gr] * sum;
    }
}

// ================= fused GCN layer =================
// one wave per node, lane = feature; gather-sum neighbors from CSR.

__global__ __launch_bounds__(256) void layer_kernel(
        const int* __restrict__ row_ptr, const int* __restrict__ col_sorted,
        const float* __restrict__ xin, const float* __restrict__ norm,
        float* __restrict__ xout, int N, int last) {
    int node = (blockIdx.x * blockDim.x + threadIdx.x) >> 6;
    int lane = threadIdx.x & 63;
    if (node >= N) return;

    int s = row_ptr[node];
    int e = row_ptr[node + 1];
    float acc = 0.0f;
    int j = s;
    for (; j + 4 <= e; j += 4) {
        int c0 = col_sorted[j];
        int c1 = col_sorted[j + 1];
        int c2 = col_sorted[j + 2];
        int c3 = col_sorted[j + 3];
        float v0 = xin[(size_t)c0 * HID + lane];
        float v1 = xin[(size_t)c1 * HID + lane];
        float v2 = xin[(size_t)c2 * HID + lane];
        float v3 = xin[(size_t)c3 * HID + lane];
        acc += (v0 + v1) + (v2 + v3);
    }
    for (; j < e; ++j)
        acc += xin[(size_t)col_sorted[j] * HID + lane];

    float self = xin[(size_t)node * HID + lane];
    float nv = norm[node];
    float h = nv * (acc + self);
    xout[(size_t)node * HID + lane] = last ? h : nv * h;
}

extern "C" void kernel_launch(void* const* d_in, const int* in_sizes, int n_in,
                              void* d_out, int out_size, void* d_ws, size_t ws_size,
                              hipStream_t stream) {
    const float* x  = (const float*)d_in[0];
    const int*   ei = (const int*)d_in[1];
    const float* W  = (const float*)d_in[2];
    const float* b  = (const float*)d_in[3];
    float* out = (float*)d_out;

    const int N = in_sizes[0] / IN_DIM;
    const int E = in_sizes[1] / 2;
    const int* rows = ei;
    const int* cols = ei + E;
    const int nc = (N + CHUNK - 1) / CHUNK;

    // ws layout (4B units): norm[N] | row_ptr[N+1] | cnt[N] | cursor[N] |
    //                       chunk_sum[nc] | chunk_off[nc] | col_sorted[E] | xs0[N*HID]
    float* norm      = (float*)d_ws;
    int*   row_ptr   = (int*)(norm + N);
    int*   cnt       = row_ptr + (N + 1);
    int*   cursor    = cnt + N;
    int*   chunk_sum = cursor + N;
    int*   chunk_off = chunk_sum + nc;
    int*   col_sorted= chunk_off + nc;
    float* xs0       = (float*)(col_sorted + E);

    // ---- CSR build ----
    hipMemsetAsync(cnt, 0, (size_t)N * sizeof(int), stream);
    hist_kernel<<<(E + 255) / 256, 256, 0, stream>>>(rows, cnt, E);
    reduce_kernel<<<nc, 256, 0, stream>>>(cnt, chunk_sum, N);
    chunkscan_kernel<<<1, 256, 0, stream>>>(chunk_sum, chunk_off, &row_ptr[N], nc);
    scanout_kernel<<<nc, 256, 0, stream>>>(cnt, chunk_off, row_ptr, cursor, norm, N);
    fill_kernel<<<(E + 255) / 256, 256, 0, stream>>>(rows, cols, cursor, col_sorted, E);

    // ---- xs0 = norm * (x @ W + b) ----
    linear_kernel<<<(N + 15) / 16, 256, 0, stream>>>(x, W, b, norm, xs0, N);

    // ---- 3 layers, ping-pong xs0 <-> d_out ----
    const int blocks = (N * 64 + 255) / 256;
    layer_kernel<<<blocks, 256, 0, stream>>>(row_ptr, col_sorted, xs0, norm, out, N, 0);
    layer_kernel<<<blocks, 256, 0, stream>>>(row_ptr, col_sorted, out, norm, xs0, N, 0);
    layer_kernel<<<blocks, 256, 0, stream>>>(row_ptr, col_sorted, xs0, norm, out, N, 1);
}

// Round 4
// 241.107 us; speedup vs baseline: 2.7335x; 1.1539x over previous
//
#include <hip/hip_runtime.h>

#define IN_DIM 128
#define HID 64
#define CHUNK 1024   // elements of cnt per scan block
#define XPAD 132     // padded LDS row stride for x tile

// ================= CSR build =================

__global__ __launch_bounds__(256) void hist_kernel(const int* __restrict__ rows,
                                                   int* __restrict__ cnt, int E) {
    int e = blockIdx.x * blockDim.x + threadIdx.x;
    if (e < E) atomicAdd(&cnt[rows[e]], 1);
}

__global__ __launch_bounds__(256) void reduce_kernel(const int* __restrict__ cnt,
                                                     int* __restrict__ chunk_sum, int N) {
    __shared__ int sdata[4];
    int base = blockIdx.x * CHUNK + threadIdx.x * 4;
    int s = 0;
    #pragma unroll
    for (int k = 0; k < 4; ++k) {
        int i = base + k;
        if (i < N) s += cnt[i];
    }
    #pragma unroll
    for (int off = 32; off >= 1; off >>= 1) s += __shfl_down(s, off, 64);
    int wave = threadIdx.x >> 6;
    if ((threadIdx.x & 63) == 0) sdata[wave] = s;
    __syncthreads();
    if (threadIdx.x == 0)
        chunk_sum[blockIdx.x] = sdata[0] + sdata[1] + sdata[2] + sdata[3];
}

__global__ __launch_bounds__(256) void chunkscan_kernel(const int* __restrict__ chunk_sum,
                                                        int* __restrict__ chunk_off,
                                                        int* __restrict__ row_ptr_last,
                                                        int nc) {
    __shared__ int s[256];
    int tid = threadIdx.x;
    int v = (tid < nc) ? chunk_sum[tid] : 0;
    s[tid] = v;
    __syncthreads();
    #pragma unroll
    for (int off = 1; off < 256; off <<= 1) {
        int t = (tid >= off) ? s[tid - off] : 0;
        __syncthreads();
        s[tid] += t;
        __syncthreads();
    }
    if (tid < nc) chunk_off[tid] = s[tid] - v;
    if (tid == 255) *row_ptr_last = s[255];
}

__global__ __launch_bounds__(256) void scanout_kernel(const int* __restrict__ cnt,
                                                      const int* __restrict__ chunk_off,
                                                      int* __restrict__ row_ptr,
                                                      int* __restrict__ cursor,
                                                      float* __restrict__ norm, int N) {
    __shared__ int s[256];
    int tid = threadIdx.x;
    int base = blockIdx.x * CHUNK + tid * 4;
    int v[4];
    int tsum = 0;
    #pragma unroll
    for (int k = 0; k < 4; ++k) {
        int i = base + k;
        v[k] = (i < N) ? cnt[i] : 0;
        tsum += v[k];
    }
    s[tid] = tsum;
    __syncthreads();
    #pragma unroll
    for (int off = 1; off < 256; off <<= 1) {
        int t = (tid >= off) ? s[tid - off] : 0;
        __syncthreads();
        s[tid] += t;
        __syncthreads();
    }
    int pos = chunk_off[blockIdx.x] + s[tid] - tsum;
    #pragma unroll
    for (int k = 0; k < 4; ++k) {
        int i = base + k;
        if (i < N) {
            row_ptr[i] = pos;
            cursor[i]  = pos;
            norm[i]    = rsqrtf(1.0f + (float)v[k]);
            pos += v[k];
        }
    }
}

__global__ __launch_bounds__(256) void fill_kernel(const int* __restrict__ rows,
                                                   const int* __restrict__ cols,
                                                   int* __restrict__ cursor,
                                                   int* __restrict__ col_sorted, int E) {
    int e = blockIdx.x * blockDim.x + threadIdx.x;
    if (e >= E) return;
    int r = rows[e];
    int pos = atomicAdd(&cursor[r], 1);
    col_sorted[pos] = cols[e];
}

// ================= fused linear (x@W + b) * norm =================
// 64 rows/block, 256 threads: thread (rg=tid>>4, c4=tid&15) computes
// rows rg*4..+3 x cols c4*4..+3. x tile in LDS (b128 reads, padded);
// W streamed from global as float4 (L2-resident, 32KB total).

__global__ __launch_bounds__(256) void linear_kernel(
        const float* __restrict__ x, const float* __restrict__ W,
        const float* __restrict__ b, const float* __restrict__ norm,
        float* __restrict__ xs, int N) {
    __shared__ float xl[64 * XPAD];
    const int tid = threadIdx.x;
    const int row0 = blockIdx.x * 64;

    // stage x tile: 64 rows x 128 cols, float4 loads, padded LDS stride
    for (int idx = tid; idx < 64 * (IN_DIM / 4); idx += 256) {
        int r = idx >> 5;          // 32 float4 per row
        int c4 = idx & 31;
        int gr = row0 + r;
        float4 v = make_float4(0.f, 0.f, 0.f, 0.f);
        if (gr < N) v = reinterpret_cast<const float4*>(x)[(size_t)gr * 32 + c4];
        *reinterpret_cast<float4*>(&xl[r * XPAD + c4 * 4]) = v;
    }
    __syncthreads();

    const int c4 = tid & 15;      // col group: cols c4*4..+3
    const int rg = tid >> 4;      // row group: rows rg*4..+3
    const float4 bv = reinterpret_cast<const float4*>(b)[c4];
    float4 acc[4];
    #pragma unroll
    for (int rr = 0; rr < 4; ++rr) acc[rr] = bv;

    const float4* Wv = reinterpret_cast<const float4*>(W);  // [128][16] float4
    for (int k0 = 0; k0 < IN_DIM; k0 += 4) {
        float4 w0 = Wv[(k0 + 0) * 16 + c4];
        float4 w1 = Wv[(k0 + 1) * 16 + c4];
        float4 w2 = Wv[(k0 + 2) * 16 + c4];
        float4 w3 = Wv[(k0 + 3) * 16 + c4];
        #pragma unroll
        for (int rr = 0; rr < 4; ++rr) {
            float4 xv = *reinterpret_cast<const float4*>(&xl[(rg * 4 + rr) * XPAD + k0]);
            acc[rr].x = fmaf(xv.x, w0.x, acc[rr].x);
            acc[rr].y = fmaf(xv.x, w0.y, acc[rr].y);
            acc[rr].z = fmaf(xv.x, w0.z, acc[rr].z);
            acc[rr].w = fmaf(xv.x, w0.w, acc[rr].w);
            acc[rr].x = fmaf(xv.y, w1.x, acc[rr].x);
            acc[rr].y = fmaf(xv.y, w1.y, acc[rr].y);
            acc[rr].z = fmaf(xv.y, w1.z, acc[rr].z);
            acc[rr].w = fmaf(xv.y, w1.w, acc[rr].w);
            acc[rr].x = fmaf(xv.z, w2.x, acc[rr].x);
            acc[rr].y = fmaf(xv.z, w2.y, acc[rr].y);
            acc[rr].z = fmaf(xv.z, w2.z, acc[rr].z);
            acc[rr].w = fmaf(xv.z, w2.w, acc[rr].w);
            acc[rr].x = fmaf(xv.w, w3.x, acc[rr].x);
            acc[rr].y = fmaf(xv.w, w3.y, acc[rr].y);
            acc[rr].z = fmaf(xv.w, w3.z, acc[rr].z);
            acc[rr].w = fmaf(xv.w, w3.w, acc[rr].w);
        }
    }

    #pragma unroll
    for (int rr = 0; rr < 4; ++rr) {
        int gr = row0 + rg * 4 + rr;
        if (gr >= N) continue;
        float nv = norm[gr];
        float4 o;
        o.x = nv * acc[rr].x;
        o.y = nv * acc[rr].y;
        o.z = nv * acc[rr].z;
        o.w = nv * acc[rr].w;
        reinterpret_cast<float4*>(xs)[(size_t)gr * 16 + c4] = o;
    }
}

// ================= fused GCN layer =================
// one wave per node, lane = feature. cols fetched 64-wide coalesced then
// broadcast via shfl; gather unrolled 8-deep, two accumulators.

__global__ __launch_bounds__(256) void layer_kernel(
        const int* __restrict__ row_ptr, const int* __restrict__ col_sorted,
        const float* __restrict__ xin, const float* __restrict__ norm,
        float* __restrict__ xout, int N, int last) {
    int node = (blockIdx.x * blockDim.x + threadIdx.x) >> 6;
    int lane = threadIdx.x & 63;
    if (node >= N) return;

    int s = row_ptr[node];
    int e = row_ptr[node + 1];
    float acc0 = 0.0f, acc1 = 0.0f;

    for (int base = s; base < e; base += 64) {
        int m = e - base;
        if (m > 64) m = 64;
        int cv = (lane < m) ? col_sorted[base + lane] : 0;
        int t = 0;
        for (; t + 8 <= m; t += 8) {
            int c0 = __shfl(cv, t + 0, 64);
            int c1 = __shfl(cv, t + 1, 64);
            int c2 = __shfl(cv, t + 2, 64);
            int c3 = __shfl(cv, t + 3, 64);
            int c4 = __shfl(cv, t + 4, 64);
            int c5 = __shfl(cv, t + 5, 64);
            int c6 = __shfl(cv, t + 6, 64);
            int c7 = __shfl(cv, t + 7, 64);
            float v0 = xin[(size_t)c0 * HID + lane];
            float v1 = xin[(size_t)c1 * HID + lane];
            float v2 = xin[(size_t)c2 * HID + lane];
            float v3 = xin[(size_t)c3 * HID + lane];
            float v4 = xin[(size_t)c4 * HID + lane];
            float v5 = xin[(size_t)c5 * HID + lane];
            float v6 = xin[(size_t)c6 * HID + lane];
            float v7 = xin[(size_t)c7 * HID + lane];
            acc0 += (v0 + v1) + (v2 + v3);
            acc1 += (v4 + v5) + (v6 + v7);
        }
        for (; t < m; ++t) {
            int c = __shfl(cv, t, 64);
            acc0 += xin[(size_t)c * HID + lane];
        }
    }

    float self = xin[(size_t)node * HID + lane];
    float nv = norm[node];
    float h = nv * (acc0 + acc1 + self);
    xout[(size_t)node * HID + lane] = last ? h : nv * h;
}

extern "C" void kernel_launch(void* const* d_in, const int* in_sizes, int n_in,
                              void* d_out, int out_size, void* d_ws, size_t ws_size,
                              hipStream_t stream) {
    const float* x  = (const float*)d_in[0];
    const int*   ei = (const int*)d_in[1];
    const float* W  = (const float*)d_in[2];
    const float* b  = (const float*)d_in[3];
    float* out = (float*)d_out;

    const int N = in_sizes[0] / IN_DIM;
    const int E = in_sizes[1] / 2;
    const int* rows = ei;
    const int* cols = ei + E;
    const int nc = (N + CHUNK - 1) / CHUNK;

    // ws layout (4B units): norm[N] | row_ptr[N+1] | cnt[N] | cursor[N] |
    //                       chunk_sum[nc] | chunk_off[nc] | col_sorted[E] | xs0[N*HID]
    float* norm      = (float*)d_ws;
    int*   row_ptr   = (int*)(norm + N);
    int*   cnt       = row_ptr + (N + 1);
    int*   cursor    = cnt + N;
    int*   chunk_sum = cursor + N;
    int*   chunk_off = chunk_sum + nc;
    int*   col_sorted= chunk_off + nc;
    float* xs0       = (float*)(col_sorted + E);

    // ---- CSR build ----
    hipMemsetAsync(cnt, 0, (size_t)N * sizeof(int), stream);
    hist_kernel<<<(E + 255) / 256, 256, 0, stream>>>(rows, cnt, E);
    reduce_kernel<<<nc, 256, 0, stream>>>(cnt, chunk_sum, N);
    chunkscan_kernel<<<1, 256, 0, stream>>>(chunk_sum, chunk_off, &row_ptr[N], nc);
    scanout_kernel<<<nc, 256, 0, stream>>>(cnt, chunk_off, row_ptr, cursor, norm, N);
    fill_kernel<<<(E + 255) / 256, 256, 0, stream>>>(rows, cols, cursor, col_sorted, E);

    // ---- xs0 = norm * (x @ W + b) ----
    linear_kernel<<<(N + 63) / 64, 256, 0, stream>>>(x, W, b, norm, xs0, N);

    // ---- 3 layers, ping-pong xs0 <-> d_out ----
    const int blocks = (N * 64 + 255) / 256;
    layer_kernel<<<blocks, 256, 0, stream>>>(row_ptr, col_sorted, xs0, norm, out, N, 0);
    layer_kernel<<<blocks, 256, 0, stream>>>(row_ptr, col_sorted, out, norm, xs0, N, 0);
    layer_kernel<<<blocks, 256, 0, stream>>>(row_ptr, col_sorted, xs0, norm, out, N, 1);
}

// Round 5
// 174.944 us; speedup vs baseline: 3.7673x; 1.3782x over previous
//
#include <hip/hip_runtime.h>

#define IN_DIM 128
#define HID 64
#define XPAD 132     // padded LDS row stride for x tile
#define EPB 4096     // edges per block in bucket build
#define MAXNB 512    // max buckets (supports N <= 65536)

// ================= bucketed CSR build =================
// bucket b = row >> 7 (128 rows per bucket), NB = ceil(N/128)

__global__ __launch_bounds__(256) void bucket_count_kernel(
        const int* __restrict__ rows, int* __restrict__ bkt_cnt, int E, int NB) {
    __shared__ int cnt[MAXNB];
    for (int i = threadIdx.x; i < NB; i += 256) cnt[i] = 0;
    __syncthreads();
    int base = blockIdx.x * EPB;
    int m = E - base; if (m > EPB) m = EPB;
    for (int k = threadIdx.x; k < m; k += 256)
        atomicAdd(&cnt[rows[base + k] >> 7], 1);
    __syncthreads();
    for (int i = threadIdx.x; i < NB; i += 256)
        if (cnt[i]) atomicAdd(&bkt_cnt[i], cnt[i]);
}

__global__ __launch_bounds__(512) void bucket_scan_kernel(
        const int* __restrict__ bkt_cnt, int* __restrict__ bucket_off,
        int* __restrict__ gcursor, int* __restrict__ row_ptr, int NB, int N, int E) {
    __shared__ int s[512];
    int tid = threadIdx.x;
    int v = (tid < NB) ? bkt_cnt[tid] : 0;
    s[tid] = v;
    __syncthreads();
    #pragma unroll
    for (int off = 1; off < 512; off <<= 1) {
        int t = (tid >= off) ? s[tid - off] : 0;
        __syncthreads();
        s[tid] += t;
        __syncthreads();
    }
    if (tid < NB) {
        bucket_off[tid] = s[tid] - v;
        gcursor[tid]    = s[tid] - v;
    }
    if (tid == 0) {
        bucket_off[NB] = E;
        row_ptr[N] = E;
    }
}

__global__ __launch_bounds__(256) void bucket_fill_kernel(
        const int* __restrict__ rows, const int* __restrict__ cols,
        int* __restrict__ gcursor, int2* __restrict__ pairs, int E, int NB) {
    __shared__ int cnt[MAXNB];
    __shared__ int bas[MAXNB];
    for (int i = threadIdx.x; i < NB; i += 256) cnt[i] = 0;
    __syncthreads();
    int base = blockIdx.x * EPB;
    int m = E - base; if (m > EPB) m = EPB;
    int r[16], c[16];
    #pragma unroll
    for (int u = 0; u < 16; ++u) {
        int k = u * 256 + threadIdx.x;
        r[u] = -1;
        if (k < m) {
            r[u] = rows[base + k];
            c[u] = cols[base + k];
            atomicAdd(&cnt[r[u] >> 7], 1);
        }
    }
    __syncthreads();
    for (int i = threadIdx.x; i < NB; i += 256) {
        int cc = cnt[i];
        bas[i] = cc ? atomicAdd(&gcursor[i], cc) : 0;
        cnt[i] = 0;  // reuse as local cursor
    }
    __syncthreads();
    #pragma unroll
    for (int u = 0; u < 16; ++u) {
        if (r[u] >= 0) {
            int bkt = r[u] >> 7;
            int pos = bas[bkt] + atomicAdd(&cnt[bkt], 1);
            pairs[pos] = make_int2(r[u], c[u]);
        }
    }
}

// one block per bucket: local counting sort -> row_ptr, norm, col_sorted
__global__ __launch_bounds__(256) void bucket_sort_kernel(
        const int2* __restrict__ pairs, const int* __restrict__ bucket_off,
        int* __restrict__ row_ptr, int* __restrict__ col_sorted,
        float* __restrict__ norm, int N) {
    __shared__ int cnt[128];
    __shared__ int scan[128];
    const int t = threadIdx.x;
    const int r0 = blockIdx.x << 7;
    const int pbase = bucket_off[blockIdx.x];
    const int pend  = bucket_off[blockIdx.x + 1];
    const int m = pend - pbase;

    if (t < 128) cnt[t] = 0;
    __syncthreads();
    for (int k = t; k < m; k += 256)
        atomicAdd(&cnt[pairs[pbase + k].x - r0], 1);
    __syncthreads();

    int v = (t < 128) ? cnt[t] : 0;
    if (t < 128) scan[t] = v;
    __syncthreads();
    #pragma unroll
    for (int off = 1; off < 128; off <<= 1) {
        int tmp = (t < 128 && t >= off) ? scan[t - off] : 0;
        __syncthreads();
        if (t < 128) scan[t] += tmp;
        __syncthreads();
    }
    if (t < 128) {
        int ex = scan[t] - v;        // exclusive
        int rr = r0 + t;
        if (rr < N) {
            row_ptr[rr] = pbase + ex;
            norm[rr]    = rsqrtf(1.0f + (float)v);
        }
        cnt[t] = ex;                 // reuse as per-row cursor
    }
    __syncthreads();
    for (int k = t; k < m; k += 256) {
        int2 p = pairs[pbase + k];
        int pos = pbase + atomicAdd(&cnt[p.x - r0], 1);
        col_sorted[pos] = p.y;
    }
}

// ================= fused linear (x@W + b) * norm =================

__global__ __launch_bounds__(256) void linear_kernel(
        const float* __restrict__ x, const float* __restrict__ W,
        const float* __restrict__ b, const float* __restrict__ norm,
        float* __restrict__ xs, int N) {
    __shared__ float xl[64 * XPAD];
    const int tid = threadIdx.x;
    const int row0 = blockIdx.x * 64;

    for (int idx = tid; idx < 64 * (IN_DIM / 4); idx += 256) {
        int r = idx >> 5;
        int c4 = idx & 31;
        int gr = row0 + r;
        float4 v = make_float4(0.f, 0.f, 0.f, 0.f);
        if (gr < N) v = reinterpret_cast<const float4*>(x)[(size_t)gr * 32 + c4];
        *reinterpret_cast<float4*>(&xl[r * XPAD + c4 * 4]) = v;
    }
    __syncthreads();

    const int c4 = tid & 15;
    const int rg = tid >> 4;
    const float4 bv = reinterpret_cast<const float4*>(b)[c4];
    float4 acc[4];
    #pragma unroll
    for (int rr = 0; rr < 4; ++rr) acc[rr] = bv;

    const float4* Wv = reinterpret_cast<const float4*>(W);
    for (int k0 = 0; k0 < IN_DIM; k0 += 4) {
        float4 w0 = Wv[(k0 + 0) * 16 + c4];
        float4 w1 = Wv[(k0 + 1) * 16 + c4];
        float4 w2 = Wv[(k0 + 2) * 16 + c4];
        float4 w3 = Wv[(k0 + 3) * 16 + c4];
        #pragma unroll
        for (int rr = 0; rr < 4; ++rr) {
            float4 xv = *reinterpret_cast<const float4*>(&xl[(rg * 4 + rr) * XPAD + k0]);
            acc[rr].x = fmaf(xv.x, w0.x, acc[rr].x);
            acc[rr].y = fmaf(xv.x, w0.y, acc[rr].y);
            acc[rr].z = fmaf(xv.x, w0.z, acc[rr].z);
            acc[rr].w = fmaf(xv.x, w0.w, acc[rr].w);
            acc[rr].x = fmaf(xv.y, w1.x, acc[rr].x);
            acc[rr].y = fmaf(xv.y, w1.y, acc[rr].y);
            acc[rr].z = fmaf(xv.y, w1.z, acc[rr].z);
            acc[rr].w = fmaf(xv.y, w1.w, acc[rr].w);
            acc[rr].x = fmaf(xv.z, w2.x, acc[rr].x);
            acc[rr].y = fmaf(xv.z, w2.y, acc[rr].y);
            acc[rr].z = fmaf(xv.z, w2.z, acc[rr].z);
            acc[rr].w = fmaf(xv.z, w2.w, acc[rr].w);
            acc[rr].x = fmaf(xv.w, w3.x, acc[rr].x);
            acc[rr].y = fmaf(xv.w, w3.y, acc[rr].y);
            acc[rr].z = fmaf(xv.w, w3.z, acc[rr].z);
            acc[rr].w = fmaf(xv.w, w3.w, acc[rr].w);
        }
    }

    #pragma unroll
    for (int rr = 0; rr < 4; ++rr) {
        int gr = row0 + rg * 4 + rr;
        if (gr >= N) continue;
        float nv = norm[gr];
        float4 o;
        o.x = nv * acc[rr].x;
        o.y = nv * acc[rr].y;
        o.z = nv * acc[rr].z;
        o.w = nv * acc[rr].w;
        reinterpret_cast<float4*>(xs)[(size_t)gr * 16 + c4] = o;
    }
}

// ================= fused GCN layer =================

__global__ __launch_bounds__(256) void layer_kernel(
        const int* __restrict__ row_ptr, const int* __restrict__ col_sorted,
        const float* __restrict__ xin, const float* __restrict__ norm,
        float* __restrict__ xout, int N, int last) {
    int node = (blockIdx.x * blockDim.x + threadIdx.x) >> 6;
    int lane = threadIdx.x & 63;
    if (node >= N) return;

    int s = row_ptr[node];
    int e = row_ptr[node + 1];
    float acc0 = 0.0f, acc1 = 0.0f;

    for (int base = s; base < e; base += 64) {
        int m = e - base;
        if (m > 64) m = 64;
        int cv = (lane < m) ? col_sorted[base + lane] : 0;
        int t = 0;
        for (; t + 8 <= m; t += 8) {
            int c0 = __shfl(cv, t + 0, 64);
            int c1 = __shfl(cv, t + 1, 64);
            int c2 = __shfl(cv, t + 2, 64);
            int c3 = __shfl(cv, t + 3, 64);
            int c4 = __shfl(cv, t + 4, 64);
            int c5 = __shfl(cv, t + 5, 64);
            int c6 = __shfl(cv, t + 6, 64);
            int c7 = __shfl(cv, t + 7, 64);
            float v0 = xin[(size_t)c0 * HID + lane];
            float v1 = xin[(size_t)c1 * HID + lane];
            float v2 = xin[(size_t)c2 * HID + lane];
            float v3 = xin[(size_t)c3 * HID + lane];
            float v4 = xin[(size_t)c4 * HID + lane];
            float v5 = xin[(size_t)c5 * HID + lane];
            float v6 = xin[(size_t)c6 * HID + lane];
            float v7 = xin[(size_t)c7 * HID + lane];
            acc0 += (v0 + v1) + (v2 + v3);
            acc1 += (v4 + v5) + (v6 + v7);
        }
        for (; t < m; ++t) {
            int c = __shfl(cv, t, 64);
            acc0 += xin[(size_t)c * HID + lane];
        }
    }

    float self = xin[(size_t)node * HID + lane];
    float nv = norm[node];
    float h = nv * (acc0 + acc1 + self);
    xout[(size_t)node * HID + lane] = last ? h : nv * h;
}

extern "C" void kernel_launch(void* const* d_in, const int* in_sizes, int n_in,
                              void* d_out, int out_size, void* d_ws, size_t ws_size,
                              hipStream_t stream) {
    const float* x  = (const float*)d_in[0];
    const int*   ei = (const int*)d_in[1];
    const float* W  = (const float*)d_in[2];
    const float* b  = (const float*)d_in[3];
    float* out = (float*)d_out;

    const int N = in_sizes[0] / IN_DIM;
    const int E = in_sizes[1] / 2;
    const int* rows = ei;
    const int* cols = ei + E;
    const int NB = (N + 127) >> 7;            // buckets of 128 rows

    // ws layout (4B units), pairs first for 8B alignment:
    // pairs[E] int2 | col_sorted[E] | bkt_cnt[MAXNB] | bucket_off[MAXNB+1] |
    // gcursor[MAXNB] | row_ptr[N+1] | norm[N] | xs0[N*HID]
    int2* pairs      = (int2*)d_ws;
    int*  col_sorted = (int*)(pairs + E);
    int*  bkt_cnt    = col_sorted + E;
    int*  bucket_off = bkt_cnt + MAXNB;
    int*  gcursor    = bucket_off + (MAXNB + 1);
    int*  row_ptr    = gcursor + MAXNB;
    float* norm      = (float*)(row_ptr + (N + 1));
    float* xs0       = norm + N;

    const int eblocks = (E + EPB - 1) / EPB;

    // ---- bucketed CSR build ----
    hipMemsetAsync(bkt_cnt, 0, (size_t)MAXNB * sizeof(int), stream);
    bucket_count_kernel<<<eblocks, 256, 0, stream>>>(rows, bkt_cnt, E, NB);
    bucket_scan_kernel<<<1, 512, 0, stream>>>(bkt_cnt, bucket_off, gcursor, row_ptr, NB, N, E);
    bucket_fill_kernel<<<eblocks, 256, 0, stream>>>(rows, cols, gcursor, pairs, E, NB);
    bucket_sort_kernel<<<NB, 256, 0, stream>>>(pairs, bucket_off, row_ptr, col_sorted, norm, N);

    // ---- xs0 = norm * (x @ W + b) ----
    linear_kernel<<<(N + 63) / 64, 256, 0, stream>>>(x, W, b, norm, xs0, N);

    // ---- 3 layers, ping-pong xs0 <-> d_out ----
    const int blocks = (N * 64 + 255) / 256;
    layer_kernel<<<blocks, 256, 0, stream>>>(row_ptr, col_sorted, xs0, norm, out, N, 0);
    layer_kernel<<<blocks, 256, 0, stream>>>(row_ptr, col_sorted, out, norm, xs0, N, 0);
    layer_kernel<<<blocks, 256, 0, stream>>>(row_ptr, col_sorted, xs0, norm, out, N, 1);
}